// Round 1
// baseline (477.011 us; speedup 1.0000x reference)
//
#include <hip/hip_runtime.h>
#include <hip/hip_bf16.h>
#include <math.h>

#define DIM 128
#define HID 256

typedef short s8x __attribute__((ext_vector_type(8)));   // 8 bf16 (as raw shorts)
typedef float f4x __attribute__((ext_vector_type(4)));   // MFMA accumulator

__device__ __forceinline__ unsigned short f2bf(float f) {
    unsigned int u = __float_as_uint(f);
    u += 0x7FFF + ((u >> 16) & 1);   // round-to-nearest-even
    return (unsigned short)(u >> 16);
}
__device__ __forceinline__ float bf2f(unsigned short b) {
    return __uint_as_float(((unsigned int)b) << 16);
}
__device__ __forceinline__ float bflo(unsigned int p) {   // low bf16 of packed pair
    return __uint_as_float(p << 16);
}
__device__ __forceinline__ float bfhi(unsigned int p) {   // high bf16 of packed pair
    return __uint_as_float(p & 0xffff0000u);
}

// ===========================================================================
// CSR build via bucketed counting sort (dst side only).
// Out-degrees via global atomics on deg[] (zeroed in prep_kernel).
// Sort payload packed in u32: (src << 7) | (dst & 127).
// ===========================================================================

// prep: zero deg[] + convert weights to bf16. grid = 128 x 256 = 32768 thr
__global__ void prep_kernel(const float* __restrict__ w1, const float* __restrict__ w2,
                            unsigned short* __restrict__ w1b, unsigned short* __restrict__ w2b,
                            int* __restrict__ deg, int nN) {
    const int t = blockIdx.x * 256 + threadIdx.x;   // exactly 32768 = HID*DIM
    w1b[t] = f2bf(w1[t]);
    w2b[t] = f2bf(w2[t]);
    for (int i = t; i < nN; i += 32768) deg[i] = 0;
}

// pass 1: per-(block,bucket) histogram of dst + global out-degree atomics
__global__ __launch_bounds__(256) void hist_kernel(
        const int* __restrict__ src, const int* __restrict__ dst,
        int* __restrict__ TD, int* __restrict__ deg, int nE, int nbuck, int chunk) {
    __shared__ int hd[1024];
    const int tid = threadIdx.x, blk = blockIdx.x;
    for (int b = tid; b < nbuck; b += 256) hd[b] = 0;
    __syncthreads();
    int beg = blk * chunk, end = min(beg + chunk, nE);
    for (int i = beg + tid; i < end; i += 256) {
        atomicAdd(&hd[dst[i] >> 7], 1);
        atomicAdd(&deg[src[i]], 1);
    }
    __syncthreads();
    for (int b = tid; b < nbuck; b += 256)   // bucket-major layout for scan
        TD[b * 256 + blk] = hd[b];
}

// hierarchical exclusive scan: 1024 elems/block
__global__ void scan_blocks(const int* in, int* out, int* bsums, int n) {
    __shared__ int part[256];
    const int tid = threadIdx.x;
    const int base = blockIdx.x * 1024 + tid * 4;
    int v[4];
    int sum = 0;
#pragma unroll
    for (int k = 0; k < 4; ++k) {
        v[k] = (base + k < n) ? in[base + k] : 0;
        sum += v[k];
    }
    part[tid] = sum;
    __syncthreads();
    for (int off = 1; off < 256; off <<= 1) {
        int t = (tid >= off) ? part[tid - off] : 0;
        __syncthreads();
        part[tid] += t;
        __syncthreads();
    }
    int excl = part[tid] - sum;
    if (tid == 255) bsums[blockIdx.x] = part[255];
#pragma unroll
    for (int k = 0; k < 4; ++k) {
        if (base + k < n) out[base + k] = excl;
        excl += v[k];
    }
}

// scan of block sums, nb <= 1024, single block of 256
__global__ void scan_sums(int* bsums, int nb) {
    __shared__ int part[256];
    const int tid = threadIdx.x;
    const int base = tid * 4;
    int v[4];
    int sum = 0;
#pragma unroll
    for (int k = 0; k < 4; ++k) {
        v[k] = (base + k < nb) ? bsums[base + k] : 0;
        sum += v[k];
    }
    part[tid] = sum;
    __syncthreads();
    for (int off = 1; off < 256; off <<= 1) {
        int t = (tid >= off) ? part[tid - off] : 0;
        __syncthreads();
        part[tid] += t;
        __syncthreads();
    }
    int excl = part[tid] - sum;
#pragma unroll
    for (int k = 0; k < 4; ++k) {
        if (base + k < nb) bsums[base + k] = excl;
        excl += v[k];
    }
}

// add block offsets; also finalize rdeg = rsqrt(deg) (deg complete after hist)
__global__ void scan_add(int* T, const int* __restrict__ bsums, int n,
                         const int* __restrict__ deg, float* __restrict__ rdeg, int nN) {
    int i = blockIdx.x * blockDim.x + threadIdx.x;
    if (i < n) T[i] += bsums[i >> 10];
    if (i < nN) rdeg[i] = rsqrtf((float)deg[i]);
}

// pass 2: scatter packed edges into bucket-ordered array using LDS cursors
__global__ __launch_bounds__(256) void scatter_edges(
        const int* __restrict__ src, const int* __restrict__ dst,
        const int* __restrict__ TD, unsigned int* __restrict__ pairs,
        int nE, int nbuck, int chunk) {
    __shared__ int cd[1024];
    const int tid = threadIdx.x, blk = blockIdx.x;
    for (int b = tid; b < nbuck; b += 256) cd[b] = TD[b * 256 + blk];
    __syncthreads();
    int beg = blk * chunk, end = min(beg + chunk, nE);
    for (int i = beg + tid; i < end; i += 256) {
        int s = src[i], d = dst[i];
        int pd = atomicAdd(&cd[d >> 7], 1);
        pairs[pd] = ((unsigned int)s << 7) | (unsigned int)(d & 127);
    }
}

// pass 3: per-bucket finalize: rowstart + locally sorted esrc
__global__ __launch_bounds__(256) void finalize_kernel(
        const unsigned int* __restrict__ pairs, const int* __restrict__ TD,
        int* __restrict__ rowstart, int* __restrict__ esrc,
        int nE, int nbuck, int nN) {
    __shared__ int hist[128], sbuf[128], cur[128];
    const int tid = threadIdx.x, b = blockIdx.x;
    int beg = TD[b * 256];
    int end = (b + 1 < nbuck) ? TD[(b + 1) * 256] : nE;
    if (tid < 128) hist[tid] = 0;
    __syncthreads();
    for (int i = beg + tid; i < end; i += 256)
        atomicAdd(&hist[(int)(pairs[i] & 127u)], 1);
    __syncthreads();
    int v = (tid < 128) ? hist[tid] : 0;
    if (tid < 128) sbuf[tid] = v;
    __syncthreads();
    for (int off = 1; off < 128; off <<= 1) {
        int t = (tid < 128 && tid >= off) ? sbuf[tid - off] : 0;
        __syncthreads();
        if (tid < 128) sbuf[tid] += t;
        __syncthreads();
    }
    if (tid < 128) {
        int excl = sbuf[tid] - v;
        cur[tid] = excl;
        int idx = (b << 7) + tid;
        if (idx <= nN) rowstart[idx] = beg + excl;   // covers rowstart[N]=E too
    }
    __syncthreads();
    for (int i = beg + tid; i < end; i += 256) {
        unsigned int p = pairs[i];
        int l = (int)(p & 127u);
        int pos = atomicAdd(&cur[l], 1);
        esrc[beg + pos] = (int)(p >> 7);
    }
}

// ---------------------------------------------------------------------------
// forward rotation -> bf16 rows
__global__ void rot_cvt_kernel(const float* __restrict__ x, const float* __restrict__ R,
                               unsigned short* __restrict__ h0, int n) {
    int u = blockIdx.x * blockDim.x + threadIdx.x;
    if (u >= n * 8) return;
    int nd = u >> 3, b = u & 7;
    const float* xp = &x[(size_t)nd * DIM + b * 16];
    const float* Rp = &R[(size_t)nd * DIM + b * 16];
    float xv[16], rv[16];
#pragma unroll
    for (int d = 0; d < 4; ++d) {
        *(float4*)&xv[d * 4] = *(const float4*)&xp[d * 4];
        *(float4*)&rv[d * 4] = *(const float4*)&Rp[d * 4];
    }
    unsigned short ob[16];
#pragma unroll
    for (int c = 0; c < 4; ++c)
#pragma unroll
        for (int e = 0; e < 4; ++e) {
            float acc = 0.f;
#pragma unroll
            for (int d = 0; d < 4; ++d) acc += rv[c * 4 + d] * xv[d * 4 + e];
            ob[c * 4 + e] = f2bf(acc);
        }
    unsigned short* op = &h0[(size_t)nd * DIM + b * 16];
    *(s8x*)&op[0] = *(s8x*)&ob[0];
    *(s8x*)&op[8] = *(s8x*)&ob[8];
}

// ---------------------------------------------------------------------------
// gather round 1 (bf16 rows): hdst[v] = sum_{e in row v} hsrc[esrc[e]] * coef(e)
__global__ __launch_bounds__(256) void gather_kernel(
        const unsigned short* __restrict__ hsrc, const int* __restrict__ esrc,
        const float* __restrict__ rdeg, const int* __restrict__ rowstart,
        unsigned short* __restrict__ hdst, int n) {
    int node = blockIdx.x * 8 + (threadIdx.x >> 5);
    int lane = threadIdx.x & 31;          // owns 4 bf16 = 8 B of the row
    if (node >= n) return;
    int beg = rowstart[node];
    int end = rowstart[node + 1];
    float rd = rdeg[node];
    float a0 = 0.f, a1 = 0.f, a2 = 0.f, a3 = 0.f;
    int i = beg;
    for (; i + 2 <= end; i += 2) {
        int s0 = esrc[i], s1 = esrc[i + 1];
        float c0 = rdeg[s0] * rd;
        float c1 = rdeg[s1] * rd;
        uint2 p0 = *(const uint2*)&hsrc[(size_t)s0 * DIM + lane * 4];
        uint2 p1 = *(const uint2*)&hsrc[(size_t)s1 * DIM + lane * 4];
        a0 += bflo(p0.x) * c0 + bflo(p1.x) * c1;
        a1 += bfhi(p0.x) * c0 + bfhi(p1.x) * c1;
        a2 += bflo(p0.y) * c0 + bflo(p1.y) * c1;
        a3 += bfhi(p0.y) * c0 + bfhi(p1.y) * c1;
    }
    if (i < end) {
        int s0 = esrc[i];
        float c0 = rdeg[s0] * rd;
        uint2 p0 = *(const uint2*)&hsrc[(size_t)s0 * DIM + lane * 4];
        a0 += bflo(p0.x) * c0;
        a1 += bfhi(p0.x) * c0;
        a2 += bflo(p0.y) * c0;
        a3 += bfhi(p0.y) * c0;
    }
    uint2 packed;
    packed.x = (unsigned int)f2bf(a0) | ((unsigned int)f2bf(a1) << 16);
    packed.y = (unsigned int)f2bf(a2) | ((unsigned int)f2bf(a3) << 16);
    *(uint2*)&hdst[(size_t)node * DIM + lane * 4] = packed;
}

// ---------------------------------------------------------------------------
// Fused gather round 2 + inverse rotation + FFN (bf16 MFMA).
// 64 nodes/block, 256 threads. abuf/hbuf union the same LDS (barrier-fenced)
// -> 33792 B -> 4 blocks/CU.
#define ABST 136
#define HBST 264
__global__ __launch_bounds__(256, 4) void ffn_kernel(
        const unsigned short* __restrict__ hM,   // [N,128] bf16 (post 1st gather)
        const int* __restrict__ esrc, const float* __restrict__ rdeg,
        const int* __restrict__ rowstart,
        const float* __restrict__ R,             // node_rep [N,128] fp32
        const unsigned short* __restrict__ w1b,  // [256][128] bf16
        const float* __restrict__ b1,            // [256]
        const unsigned short* __restrict__ w2b,  // [128][256] bf16
        const float* __restrict__ b2,            // [128]
        float* __restrict__ out, int n) {
    __shared__ unsigned short smem[64 * HBST];   // 33792 B
    unsigned short* abuf = smem;   // rows at stride ABST (phases A/B/GEMM1)
    unsigned short* hbuf = smem;   // rows at stride HBST (after barrier)
    const int tid  = threadIdx.x;
    const int node0 = blockIdx.x * 64;
    const int wave = tid >> 6;
    const int lane64 = tid & 63;
    const int lr = lane64 & 15;   // tile row (A) / tile col (B,C)
    const int lq = lane64 >> 4;   // quad -> k-block / C row group

    // ---- phase A: gather round 2 from hM straight into LDS (bf16)
    {
        const int lane = tid & 31;   // owns 4 bf16 = 8 B of a row
        const int sub  = tid >> 5;   // 8 nodes per pass
        for (int p = 0; p < 8; ++p) {
            const int nd = p * 8 + sub;
            const int gn = node0 + nd;
            float a0 = 0.f, a1 = 0.f, a2 = 0.f, a3 = 0.f;
            if (gn < n) {
                const int beg = rowstart[gn], end = rowstart[gn + 1];
                const float rd = rdeg[gn];
                int i = beg;
                for (; i + 4 <= end; i += 4) {
                    int s0 = esrc[i], s1 = esrc[i + 1], s2 = esrc[i + 2], s3 = esrc[i + 3];
                    float c0 = rdeg[s0] * rd, c1 = rdeg[s1] * rd;
                    float c2 = rdeg[s2] * rd, c3 = rdeg[s3] * rd;
                    uint2 p0 = *(const uint2*)&hM[(size_t)s0 * DIM + lane * 4];
                    uint2 p1 = *(const uint2*)&hM[(size_t)s1 * DIM + lane * 4];
                    uint2 p2 = *(const uint2*)&hM[(size_t)s2 * DIM + lane * 4];
                    uint2 p3 = *(const uint2*)&hM[(size_t)s3 * DIM + lane * 4];
                    a0 += bflo(p0.x) * c0 + bflo(p1.x) * c1 + bflo(p2.x) * c2 + bflo(p3.x) * c3;
                    a1 += bfhi(p0.x) * c0 + bfhi(p1.x) * c1 + bfhi(p2.x) * c2 + bfhi(p3.x) * c3;
                    a2 += bflo(p0.y) * c0 + bflo(p1.y) * c1 + bflo(p2.y) * c2 + bflo(p3.y) * c3;
                    a3 += bfhi(p0.y) * c0 + bfhi(p1.y) * c1 + bfhi(p2.y) * c2 + bfhi(p3.y) * c3;
                }
                for (; i < end; ++i) {
                    int s0 = esrc[i];
                    float c0 = rdeg[s0] * rd;
                    uint2 p0 = *(const uint2*)&hM[(size_t)s0 * DIM + lane * 4];
                    a0 += bflo(p0.x) * c0;
                    a1 += bfhi(p0.x) * c0;
                    a2 += bflo(p0.y) * c0;
                    a3 += bfhi(p0.y) * c0;
                }
            }
            uint2 packed;
            packed.x = (unsigned int)f2bf(a0) | ((unsigned int)f2bf(a1) << 16);
            packed.y = (unsigned int)f2bf(a2) | ((unsigned int)f2bf(a3) << 16);
            *(uint2*)&abuf[nd * ABST + lane * 4] = packed;
        }
    }
    __syncthreads();

    // ---- phase B: in-place inverse rotation (each thread owns its 16 elems)
    for (int u = tid; u < 512; u += 256) {
        const int nd = u >> 3, b = u & 7;
        const int gn = node0 + nd;
        unsigned short hraw[16];
        *(s8x*)&hraw[0] = *(const s8x*)&abuf[nd * ABST + b * 16];
        *(s8x*)&hraw[8] = *(const s8x*)&abuf[nd * ABST + b * 16 + 8];
        float hv[16], rv[16];
#pragma unroll
        for (int d = 0; d < 16; ++d) hv[d] = bf2f(hraw[d]);
        if (gn < n) {
            const float* Rp = &R[(size_t)gn * DIM + b * 16];
#pragma unroll
            for (int d = 0; d < 4; ++d)
                *(float4*)&rv[d * 4] = *(const float4*)&Rp[d * 4];
        } else {
#pragma unroll
            for (int d = 0; d < 16; ++d) rv[d] = 0.f;
        }
        // g[c][e] = sum_d R[b][d][c] * h[b][d][e]
        unsigned short gb[16];
#pragma unroll
        for (int c = 0; c < 4; ++c)
#pragma unroll
            for (int e = 0; e < 4; ++e) {
                float acc = 0.f;
#pragma unroll
                for (int d = 0; d < 4; ++d) acc += rv[d * 4 + c] * hv[d * 4 + e];
                gb[c * 4 + e] = f2bf(acc);
            }
        *(s8x*)&abuf[nd * ABST + b * 16] = *(s8x*)&gb[0];
        *(s8x*)&abuf[nd * ABST + b * 16 + 8] = *(s8x*)&gb[8];
    }
    __syncthreads();

    // ---- GEMM1: hid[64][256] = gelu(A[64,128] @ w1^T + b1), wave owns 64 cols
    f4x acc1[4][4];
#pragma unroll
    for (int mt = 0; mt < 4; ++mt)
#pragma unroll
        for (int nt = 0; nt < 4; ++nt) acc1[mt][nt] = (f4x){0.f, 0.f, 0.f, 0.f};

    const int nw = wave * 64;
    for (int ks = 0; ks < 4; ++ks) {
        const int k0 = ks * 32 + lq * 8;
        s8x af[4], bfv[4];
#pragma unroll
        for (int mt = 0; mt < 4; ++mt)
            af[mt] = *(const s8x*)&abuf[(mt * 16 + lr) * ABST + k0];
#pragma unroll
        for (int nt = 0; nt < 4; ++nt)
            bfv[nt] = *(const s8x*)&w1b[(size_t)(nw + nt * 16 + lr) * 128 + k0];
#pragma unroll
        for (int mt = 0; mt < 4; ++mt)
#pragma unroll
            for (int nt = 0; nt < 4; ++nt)
                acc1[mt][nt] = __builtin_amdgcn_mfma_f32_16x16x32_bf16(
                    af[mt], bfv[nt], acc1[mt][nt], 0, 0, 0);
    }
    __syncthreads();   // abuf dead; hbuf may now overwrite it

    // epilogue: bias + exact gelu -> bf16 hbuf[m][n]
#pragma unroll
    for (int nt = 0; nt < 4; ++nt) {
        int nn = nw + nt * 16 + lr;
        float bias = b1[nn];
#pragma unroll
        for (int mt = 0; mt < 4; ++mt) {
#pragma unroll
            for (int r = 0; r < 4; ++r) {
                float v = acc1[mt][nt][r] + bias;
                v = 0.5f * v * (1.f + erff(v * 0.70710678118654752f));
                hbuf[(mt * 16 + lq * 4 + r) * HBST + nn] = f2bf(v);
            }
        }
    }
    __syncthreads();

    // ---- GEMM2: out[64][128] = hid[64,256] @ w2^T + b2, wave owns 32 cols
    f4x acc2[4][2];
#pragma unroll
    for (int mt = 0; mt < 4; ++mt)
#pragma unroll
        for (int nt = 0; nt < 2; ++nt) acc2[mt][nt] = (f4x){0.f, 0.f, 0.f, 0.f};

    const int nw2 = wave * 32;
    for (int ks = 0; ks < 8; ++ks) {
        const int k0 = ks * 32 + lq * 8;
        s8x af[4], bf2v[2];
#pragma unroll
        for (int mt = 0; mt < 4; ++mt)
            af[mt] = *(const s8x*)&hbuf[(mt * 16 + lr) * HBST + k0];
#pragma unroll
        for (int nt = 0; nt < 2; ++nt)
            bf2v[nt] = *(const s8x*)&w2b[(size_t)(nw2 + nt * 16 + lr) * 256 + k0];
#pragma unroll
        for (int mt = 0; mt < 4; ++mt)
#pragma unroll
            for (int nt = 0; nt < 2; ++nt)
                acc2[mt][nt] = __builtin_amdgcn_mfma_f32_16x16x32_bf16(
                    af[mt], bf2v[nt], acc2[mt][nt], 0, 0, 0);
    }
    // epilogue: bias + store fp32
#pragma unroll
    for (int nt = 0; nt < 2; ++nt) {
        int n2 = nw2 + nt * 16 + lr;
        float bias = b2[n2];
#pragma unroll
        for (int mt = 0; mt < 4; ++mt) {
#pragma unroll
            for (int r = 0; r < 4; ++r) {
                int gn = node0 + mt * 16 + lq * 4 + r;
                if (gn < n) out[(size_t)gn * DIM + n2] = acc2[mt][nt][r] + bias;
            }
        }
    }
}

// ---------------------------------------------------------------------------
extern "C" void kernel_launch(void* const* d_in, const int* in_sizes, int n_in,
                              void* d_out, int out_size, void* d_ws, size_t ws_size,
                              hipStream_t stream) {
    const float* x   = (const float*)d_in[0];
    const float* R   = (const float*)d_in[1];
    const int*   src = (const int*)d_in[2];
    const int*   dst = (const int*)d_in[3];
    const float* w1  = (const float*)d_in[4];
    const float* b1  = (const float*)d_in[5];
    const float* w2  = (const float*)d_in[6];
    const float* b2  = (const float*)d_in[7];
    float* out = (float*)d_out;

    const int N = in_sizes[0] / DIM;   // 100000
    const int E = in_sizes[2];         // 1600000

    const int nbuck = (N + 127) >> 7;          // 782
    const int chunk = (E + 255) / 256;         // 6250
    const int nScan = nbuck * 256;             // 200192
    const int nbScan = (nScan + 1023) / 1024;  // 196

    // ws layout:
    // hA [N*128 bf16] | hM [N*128 bf16]  (hM aliased by pairs32[E u32] scratch)
    // rdeg [N f32] | deg [N int] | rowstart [N+1] | esrc [E] | TD [nScan] |
    // bsums [1024] | w1b [32768 us] | w2b [32768 us]
    unsigned short* hA = (unsigned short*)d_ws;
    unsigned short* hM = hA + (size_t)N * DIM;
    unsigned int* pairs = (unsigned int*)hM;   // scratch, dead before gather1
    float* rdeg     = (float*)(hM + (size_t)N * DIM);
    int*   deg      = (int*)(rdeg + N);
    int*   rowstart = deg + N;
    int*   esrc     = rowstart + (N + 1);
    int*   TD       = esrc + E;
    int*   bsums    = TD + nScan;
    unsigned short* w1b = (unsigned short*)(bsums + 1024);
    unsigned short* w2b = w1b + 32768;

    const int BLK = 256;

    // 0) zero deg + weight conversion
    prep_kernel<<<128, BLK, 0, stream>>>(w1, w2, w1b, w2b, deg, N);

    // 1) CSR build: dst-bucket histogram + global out-degree atomics
    hist_kernel<<<256, BLK, 0, stream>>>(src, dst, TD, deg, E, nbuck, chunk);
    scan_blocks<<<nbScan, BLK, 0, stream>>>(TD, TD, bsums, nScan);
    scan_sums<<<1, BLK, 0, stream>>>(bsums, nbScan);
    scan_add<<<(nScan + BLK - 1) / BLK, BLK, 0, stream>>>(TD, bsums, nScan, deg, rdeg, N);
    scatter_edges<<<256, BLK, 0, stream>>>(src, dst, TD, pairs, E, nbuck, chunk);
    finalize_kernel<<<nbuck, BLK, 0, stream>>>(pairs, TD, rowstart, esrc, E, nbuck, N);

    // 2) forward rotation into hA (bf16)
    const int nbRot = ((size_t)N * 8 + BLK - 1) / BLK;
    rot_cvt_kernel<<<nbRot, BLK, 0, stream>>>(x, R, hA, N);

    // 3) propagation round 1 (bf16 rows, coef = rdeg[s]*rdeg[d])
    gather_kernel<<<(N + 7) / 8, BLK, 0, stream>>>(hA, esrc, rdeg, rowstart, hM, N);

    // 4) fused: gather round 2 + inverse rotation + FFN -> out
    ffn_kernel<<<(N + 63) / 64, BLK, 0, stream>>>(hM, esrc, rdeg, rowstart, R,
                                                  w1b, b1, w2b, b2, out, N);
}